// Round 3
// baseline (39.432 us; speedup 1.0000x reference)
//
#include <hip/hip_runtime.h>

// Problem constants (fixed by setup_inputs): BS=2, NCAM=3, N=64, S=256
constexpr int S_IMG = 256;
constexpr int NPT   = 64;
constexpr int BC    = 6;                    // BS*NCAM
constexpr int NCAM_ = 3;
// 1536 blob blocks: one per (bc, n, row-quarter), each writes 64 KB linearly.
// 768 mask blocks: one per (bc, row-pair), recompute + max over n in-register.
// Interleaved 2:1 in the grid (2304 = 3 * 768) so both roles co-run on every CU.
constexpr int NTOTAL = 2304;

typedef float vf4 __attribute__((ext_vector_type(4)));
typedef float vf2 __attribute__((ext_vector_type(2)));

__device__ __forceinline__ float blob_eval(float u, float e) {
    // exp(-(u^e)) ; u^e = exp2(e*log2(u)) ; exp(-v) = exp2(-log2e*v)
    // u==0: log2->-inf, exp2->0, result exp2(-0)=1 == reference limit.
    float v = exp2f(e * __log2f(u));
    return exp2f(-1.4426950408889634f * v);
}

__global__ __launch_bounds__(256) void render_all(
    const float* __restrict__ points,       // (BC,N,2)
    const float* __restrict__ sigmas,       // (BS,N)
    const float* __restrict__ exponents,    // (BS,N)
    const float* __restrict__ intensities,  // (BS,N)
    const float* __restrict__ cam_sig,      // (BS,NCAM)
    const float* __restrict__ cam_exp,      // (BS,NCAM)
    const float* __restrict__ cam_int,      // (BS,NCAM)
    float* __restrict__ masks,              // (BC,S,S)
    float* __restrict__ blobs)              // (BC,N,S,S)
{
    const int   blk  = blockIdx.x;
    const int   t    = threadIdx.x;
    const float step = 2.0f / 255.0f;       // linspace(-1,1,256) step

    if (blk % 3 != 2) {
        // ---- blob writer: owns (bc, n, quarter); 64 rows, 64 KB linear
        const int blob_idx = blk - blk / 3;      // 0..1535
        const int slice = blob_idx >> 2;         // (bc,n) in [0,384)
        const int q     = blob_idx & 3;          // row quarter
        const int bc    = slice >> 6;
        const int n     = slice & 63;
        const int b     = bc / NCAM_;

        float px = points[slice * 2 + 0];
        float py = points[slice * 2 + 1];
        px = fminf(fmaxf((px - 128.0f) * (1.0f / 128.0f), -1.0f), 1.0f);
        py = fminf(fmaxf((py - 128.0f) * (1.0f / 128.0f), -1.0f), 1.0f);
        float sg = sigmas[b * NPT + n] * cam_sig[bc];
        float k  = 1.0f / (2.0f * sg * sg);
        float e  = exponents[b * NPT + n] * cam_exp[bc];

        float* bp = blobs + ((size_t)slice << 16);

        const int x0 = (t & 63) << 2;       // 4 px along x (float4)
        const int ty = t >> 6;              // row 0..3 within 4-row sweep

        float kdx2[4];
        #pragma unroll
        for (int j = 0; j < 4; ++j) {
            float gx = fmaf((float)(x0 + j), step, -1.0f);
            float dx = gx - px;
            kdx2[j] = k * dx * dx;
        }

        const int ybase = q << 6;           // 64 rows per quarter
        #pragma unroll 4
        for (int it = 0; it < 16; ++it) {
            const int y = ybase + ((it << 2) | ty);
            float gy   = fmaf((float)y, step, -1.0f);
            float dyv  = gy - py;
            float kdy2 = k * dyv * dyv;
            vf4 o;
            o.x = blob_eval(kdx2[0] + kdy2, e);
            o.y = blob_eval(kdx2[1] + kdy2, e);
            o.z = blob_eval(kdx2[2] + kdy2, e);
            o.w = blob_eval(kdx2[3] + kdy2, e);
            *reinterpret_cast<vf4*>(bp + ((size_t)y << 8) + x0) = o;
        }
    } else {
        // ---- mask block: recompute blobs per pixel, max over n in-register
        const int mask_idx = blk / 3;       // 0..767
        const int bc = mask_idx >> 7;
        const int y0 = (mask_idx & 127) << 1;
        const int b  = bc / NCAM_;

        __shared__ float spx[NPT], spy[NPT], sk[NPT], se[NPT], si[NPT];
        if (t < NPT) {
            float px = points[(bc * NPT + t) * 2 + 0];
            float py = points[(bc * NPT + t) * 2 + 1];
            px = fminf(fmaxf((px - 128.0f) * (1.0f / 128.0f), -1.0f), 1.0f);
            py = fminf(fmaxf((py - 128.0f) * (1.0f / 128.0f), -1.0f), 1.0f);
            float sg = sigmas[b * NPT + t] * cam_sig[bc];
            spx[t] = px;
            spy[t] = py;
            sk[t]  = 1.0f / (2.0f * sg * sg);
            se[t]  = exponents[b * NPT + t] * cam_exp[bc];
            si[t]  = intensities[b * NPT + t] * cam_int[bc];
        }
        __syncthreads();

        const int lin = t << 1;             // 2 px/thread (float2)
        const int y   = y0 + (lin >> 8);
        const int x   = lin & 255;

        const float gx0 = fmaf((float)x, step, -1.0f);
        const float gx1 = gx0 + step;
        const float gy  = fmaf((float)y, step, -1.0f);

        float m0 = 0.0f, m1 = 0.0f;
        #pragma unroll 4
        for (int n = 0; n < NPT; ++n) {
            float kk   = sk[n];
            float dx0  = gx0 - spx[n];
            float dx1  = gx1 - spx[n];
            float dyv  = gy  - spy[n];
            float kdy2 = kk * dyv * dyv;
            float e    = se[n];
            float b0   = blob_eval(fmaf(kk * dx0, dx0, kdy2), e);
            float b1   = blob_eval(fmaf(kk * dx1, dx1, kdy2), e);
            float it   = si[n];
            m0 = fmaxf(m0, b0 * it);
            m1 = fmaxf(m1, b1 * it);
        }

        vf2 mm;
        mm.x = fminf(m0, 1.0f);
        mm.y = fminf(m1, 1.0f);
        *reinterpret_cast<vf2*>(masks + ((size_t)bc << 16) + ((size_t)y << 8) + x) = mm;
    }
}

extern "C" void kernel_launch(void* const* d_in, const int* in_sizes, int n_in,
                              void* d_out, int out_size, void* d_ws, size_t ws_size,
                              hipStream_t stream) {
    const float* points      = (const float*)d_in[0];
    const float* sigmas      = (const float*)d_in[1];
    const float* exponents   = (const float*)d_in[2];
    const float* intensities = (const float*)d_in[3];
    const float* cam_sig     = (const float*)d_in[4];
    const float* cam_exp     = (const float*)d_in[5];
    const float* cam_int     = (const float*)d_in[6];
    // d_in[7] = image_size (256), fixed by problem shape — hardcoded.

    float* masks = (float*)d_out;                                // BC*S*S
    float* blobs = (float*)d_out + (size_t)BC * S_IMG * S_IMG;   // BC*N*S*S

    dim3 grid(NTOTAL);   // 2304
    dim3 block(256);
    render_all<<<grid, block, 0, stream>>>(
        points, sigmas, exponents, intensities, cam_sig, cam_exp, cam_int,
        masks, blobs);
}

// Round 4
// 29.670 us; speedup vs baseline: 1.3290x; 1.3290x over previous
//
#include <hip/hip_runtime.h>

// Problem constants (fixed by setup_inputs): BS=2, NCAM=3, N=64, S=256
constexpr int S_IMG = 256;
constexpr int NPT   = 64;
constexpr int BC    = 6;      // BS*NCAM
constexpr int NCAM_ = 3;
constexpr int NHALF = 32;     // points per block (n-split 2-way)

typedef float vf2 __attribute__((ext_vector_type(2)));

__device__ __forceinline__ float blob_eval(float u, float e) {
    // exp(-(u^e)) ; u^e = exp2(e*log2(u)) ; exp(-v) = exp2(-log2e*v)
    // u==0: log2->-inf, exp2->0, result exp2(-0)=1 == reference limit.
    float v = exp2f(e * __log2f(u));
    return exp2f(-1.4426950408889634f * v);
}

// Grid: BC * (S/2) * 2 = 1536 blocks, 256 threads.
// Block (mask_idx, half): owns 2 image rows x 32 points.
// Fused: writes 32 blob slices' rows + accumulates partial mask, atomicMax out.
__global__ __launch_bounds__(256) void render_fused(
    const float* __restrict__ points,       // (BC,N,2)
    const float* __restrict__ sigmas,       // (BS,N)
    const float* __restrict__ exponents,    // (BS,N)
    const float* __restrict__ intensities,  // (BS,N)
    const float* __restrict__ cam_sig,      // (BS,NCAM)
    const float* __restrict__ cam_exp,      // (BS,NCAM)
    const float* __restrict__ cam_int,      // (BS,NCAM)
    float* __restrict__ masks,              // (BC,S,S) -- pre-zeroed
    float* __restrict__ blobs)              // (BC,N,S,S)
{
    const int blk      = blockIdx.x;
    const int half     = blk & 1;           // n in [half*32, half*32+32)
    const int mask_idx = blk >> 1;          // 0..767
    const int bc       = mask_idx >> 7;
    const int y0       = (mask_idx & 127) << 1;
    const int b        = bc / NCAM_;
    const int t        = threadIdx.x;

    __shared__ float spx[NHALF], spy[NHALF], sk[NHALF], se[NHALF], si[NHALF];
    if (t < NHALF) {
        const int n = (half << 5) + t;      // global point index
        float px = points[(bc * NPT + n) * 2 + 0];
        float py = points[(bc * NPT + n) * 2 + 1];
        px = fminf(fmaxf((px - 128.0f) * (1.0f / 128.0f), -1.0f), 1.0f);
        py = fminf(fmaxf((py - 128.0f) * (1.0f / 128.0f), -1.0f), 1.0f);
        float sg = sigmas[b * NPT + n] * cam_sig[bc];
        spx[t] = px;
        spy[t] = py;
        sk[t]  = 1.0f / (2.0f * sg * sg);
        se[t]  = exponents[b * NPT + n] * cam_exp[bc];
        si[t]  = intensities[b * NPT + n] * cam_int[bc];
    }
    __syncthreads();

    const int lin = t << 1;                 // 2 px/thread (float2)
    const int y   = y0 + (lin >> 8);
    const int x   = lin & 255;

    const float step = 2.0f / 255.0f;       // linspace(-1,1,256) step
    const float gx0  = fmaf((float)x, step, -1.0f);
    const float gx1  = gx0 + step;
    const float gy   = fmaf((float)y, step, -1.0f);

    float m0 = 0.0f, m1 = 0.0f;
    // base ptr for this half's first slice, at (y, x)
    float* bp = blobs + ((size_t)(bc * NPT + (half << 5)) << 16)
                      + ((size_t)y << 8) + x;
    const size_t nstride = (size_t)S_IMG * S_IMG;

    #pragma unroll 4
    for (int n = 0; n < NHALF; ++n) {
        float kk   = sk[n];
        float dx0  = gx0 - spx[n];
        float dx1  = gx1 - spx[n];
        float dyv  = gy  - spy[n];
        float kdy2 = kk * dyv * dyv;
        float e    = se[n];
        float b0   = blob_eval(fmaf(kk * dx0, dx0, kdy2), e);
        float b1   = blob_eval(fmaf(kk * dx1, dx1, kdy2), e);
        vf2 o; o.x = b0; o.y = b1;
        *reinterpret_cast<vf2*>(bp + n * nstride) = o;
        float it = si[n];
        m0 = fmaxf(m0, b0 * it);
        m1 = fmaxf(m1, b1 * it);
    }

    // partial mask: clamp then atomic-max (positive floats order as uints)
    m0 = fminf(m0, 1.0f);
    m1 = fminf(m1, 1.0f);
    unsigned int* mp = (unsigned int*)(masks + ((size_t)bc << 16)
                                             + ((size_t)y << 8) + x);
    atomicMax(mp + 0, __float_as_uint(m0));
    atomicMax(mp + 1, __float_as_uint(m1));
}

extern "C" void kernel_launch(void* const* d_in, const int* in_sizes, int n_in,
                              void* d_out, int out_size, void* d_ws, size_t ws_size,
                              hipStream_t stream) {
    const float* points      = (const float*)d_in[0];
    const float* sigmas      = (const float*)d_in[1];
    const float* exponents   = (const float*)d_in[2];
    const float* intensities = (const float*)d_in[3];
    const float* cam_sig     = (const float*)d_in[4];
    const float* cam_exp     = (const float*)d_in[5];
    const float* cam_int     = (const float*)d_in[6];
    // d_in[7] = image_size (256), fixed by problem shape — hardcoded.

    float* masks = (float*)d_out;                                // BC*S*S
    float* blobs = (float*)d_out + (size_t)BC * S_IMG * S_IMG;   // BC*N*S*S

    // zero masks so atomicMax accumulates correctly (graph-capturable)
    hipMemsetAsync(masks, 0, (size_t)BC * S_IMG * S_IMG * sizeof(float), stream);

    dim3 grid(BC * (S_IMG / 2) * 2);   // 1536
    dim3 block(256);
    render_fused<<<grid, block, 0, stream>>>(
        points, sigmas, exponents, intensities, cam_sig, cam_exp, cam_int,
        masks, blobs);
}